// Round 14
// baseline (231.272 us; speedup 1.0000x reference)
//
#include <hip/hip_runtime.h>

#define IN_F 128
#define HID_F 64
#define BKT_SHIFT 9            // 512 nodes per bucket (R4-verified geometry)
#define BKT_SIZE 512
#define CHUNK 4096             // edges per block in binning kernels

typedef unsigned short ushort_t;
typedef __attribute__((ext_vector_type(8))) short bf16x8;
typedef __attribute__((ext_vector_type(8))) unsigned short u16x8;
typedef __attribute__((ext_vector_type(4))) float f32x4;

__device__ inline ushort_t f2bf(float f) {     // RNE fp32 -> bf16 bits
    unsigned u = __float_as_uint(f);
    u += 0x7FFFu + ((u >> 16) & 1u);
    return (ushort_t)(u >> 16);
}
__device__ inline float bf2f(ushort_t u) {
    return __uint_as_float((unsigned)u << 16);
}

// ---------------- gemm1 block body: xw = bf16(x @ W1), UNSCALED ----------------
// No dinv dependency -> these blocks are appended onto the latency-bound CSR
// launches (colscan/scatter), overlapping gemm1 with the CSR build. dinv[src] is
// applied per-edge in k_agg_gemm phase A instead (R10's deg-atomic mistake avoided:
// dinv still comes from fill2's free LDS counting).
__device__ inline void gemm1_block(int gb, const float* __restrict__ A,
        const ushort_t* __restrict__ Bp, ushort_t* __restrict__ out, int N) {
    int tid = threadIdx.x;
    int wave = tid >> 6, lane = tid & 63;
    int m = lane & 15, q = lane >> 4;
    int row0 = gb * 64 + wave * 16;
    int arow = row0 + m;
    int arowc = (arow < N) ? arow : (N - 1);
    f32x4 acc[4] = {};
    #pragma unroll
    for (int s = 0; s < 4; ++s) {              // K = 128
        const float* ap = A + (size_t)arowc * 128 + s * 32 + q * 8;
        float4 x0 = *(const float4*)ap;
        float4 x1 = *(const float4*)(ap + 4);
        bf16x8 af;
        af[0] = (short)f2bf(x0.x); af[1] = (short)f2bf(x0.y);
        af[2] = (short)f2bf(x0.z); af[3] = (short)f2bf(x0.w);
        af[4] = (short)f2bf(x1.x); af[5] = (short)f2bf(x1.y);
        af[6] = (short)f2bf(x1.z); af[7] = (short)f2bf(x1.w);
        #pragma unroll
        for (int t = 0; t < 4; ++t) {
            bf16x8 bf = *(const bf16x8*)(Bp + (size_t)((s * 4 + t) * 64 + lane) * 8);
            acc[t] = __builtin_amdgcn_mfma_f32_16x16x32_bf16(af, bf, acc[t], 0, 0, 0);
        }
    }
    // C/D layout: col = lane&15, row = q*4 + r  [m89-verified]
    int orow0 = row0 + q * 4;
    #pragma unroll
    for (int r = 0; r < 4; ++r) {
        int row = orow0 + r;
        if (row < N) {
            #pragma unroll
            for (int t = 0; t < 4; ++t)
                out[(size_t)row * 64 + t * 16 + m] = f2bf(acc[t][r]);
        }
    }
}

// ---------------- CSR build: atomic-free 2-level bucket sort by dst ----------------
// pack: (dst & 511) << 23 | src   (needs src < 2^23, nodes/bucket <= 512)

__global__ __launch_bounds__(256) void k_hist_pack(const int* __restrict__ dst,
        int* __restrict__ ghist, int E, int nbE,
        const float* __restrict__ W1, const float* __restrict__ W2,
        ushort_t* __restrict__ Bp1, ushort_t* __restrict__ Bp2) {
    int tid = threadIdx.x;
    if ((int)blockIdx.x >= nbE) {
        // W pre-pack into MFMA B-fragment order (bf16).
        // B-frag (16x16x32): lane holds B[k = (lane>>4)*8 + j][n = lane&15], j=0..7.
        int id = ((int)blockIdx.x - nbE) * 256 + tid;
        int iw = (id < 8192) ? id : id - 8192;
        int j = iw & 7, lane = (iw >> 3) & 63, t = (iw >> 9) & 3, s = iw >> 11;
        int k = s * 32 + ((lane >> 4) << 3) + j;
        int n = t * 16 + (lane & 15);
        if (id < 8192)        Bp1[iw] = f2bf(W1[k * 64 + n]);   // K=128: s in 0..3
        else if (id < 12288)  Bp2[iw] = f2bf(W2[k * 64 + n]);   // K=64 : s in 0..1
        return;
    }
    __shared__ int hist[256];
    hist[tid] = 0;
    __syncthreads();
    int e0 = blockIdx.x * CHUNK, e1 = min(e0 + CHUNK, E);
    for (int e = e0 + tid; e < e1; e += 256)
        atomicAdd(&hist[dst[e] >> BKT_SHIFT], 1);
    __syncthreads();
    ghist[blockIdx.x * 256 + tid] = hist[tid];
}

// 256 scan blocks (one per bucket) + appended gemm1 blocks (need only x, Bp1).
__global__ __launch_bounds__(256) void k_colscan(int* __restrict__ ghist,
        int* __restrict__ gcount, int nb,
        const float* __restrict__ x, const ushort_t* __restrict__ Bp1,
        ushort_t* __restrict__ xw, int N, int gbase) {
    if ((int)blockIdx.x >= 256) {
        gemm1_block(gbase + (int)blockIdx.x - 256, x, Bp1, xw, N);
        return;
    }
    __shared__ int s[256];
    int t = threadIdx.x;
    int b = blockIdx.x;
    int j0 = 2 * t, j1 = 2 * t + 1;
    int v0 = (j0 < nb) ? ghist[j0 * 256 + b] : 0;
    int v1 = (j1 < nb) ? ghist[j1 * 256 + b] : 0;
    int p = v0 + v1;
    s[t] = p;
    __syncthreads();
    for (int off = 1; off < 256; off <<= 1) {
        int v = (t >= off) ? s[t - off] : 0;
        __syncthreads();
        s[t] += v;
        __syncthreads();
    }
    int excl = s[t] - p;
    if (j0 < nb) ghist[j0 * 256 + b] = excl;
    if (j1 < nb) ghist[j1 * 256 + b] = excl + v0;
    if (t == 255) gcount[b] = s[255];
}

// scatter into bucket-contiguous gbin + appended gemm1 blocks.
__global__ __launch_bounds__(256) void k_scatter(const int* __restrict__ src,
        const int* __restrict__ dst, const int* __restrict__ ghist,
        const int* __restrict__ gcount, unsigned* __restrict__ gbin, int E, int nbE,
        const float* __restrict__ x, const ushort_t* __restrict__ Bp1,
        ushort_t* __restrict__ xw, int N, int gbase) {
    if ((int)blockIdx.x >= nbE) {
        gemm1_block(gbase + (int)blockIdx.x - nbE, x, Bp1, xw, N);
        return;
    }
    __shared__ int cur[256];
    __shared__ int s[256];
    int tid = threadIdx.x;
    int gc = gcount[tid];
    s[tid] = gc;
    __syncthreads();
    for (int off = 1; off < 256; off <<= 1) {
        int v = (tid >= off) ? s[tid - off] : 0;
        __syncthreads();
        s[tid] += v;
        __syncthreads();
    }
    cur[tid] = ghist[blockIdx.x * 256 + tid] + (s[tid] - gc);
    __syncthreads();
    int e0 = blockIdx.x * CHUNK, e1 = min(e0 + CHUNK, E);
    for (int e = e0 + tid; e < e1; e += 256) {
        int d = dst[e];
        int b = d >> BKT_SHIFT;
        int p = atomicAdd(&cur[b], 1);
        gbin[p] = ((unsigned)(d & (BKT_SIZE - 1)) << 23) | (unsigned)src[e];
    }
}

// one block per bucket: per-(node,octant) LDS counting sort (R13-verified).
// key = (node-local)*8 + src-octant. col comes out octant-sorted per row.
__global__ __launch_bounds__(256) void k_fill2(const unsigned* __restrict__ gbin,
        const int* __restrict__ gcount, int* __restrict__ rowptr,
        float* __restrict__ dinv, int* __restrict__ col, int N, int E) {
    __shared__ int cnt[4096];            // 16 KB: 512 nodes x 8 octants
    __shared__ int s[256];
    int tid = threadIdx.x;
    int b = blockIdx.x;
    // bucket window [e0, e1) from local scan of gcount
    int gc = gcount[tid];
    s[tid] = gc;
    __syncthreads();
    for (int off = 1; off < 256; off <<= 1) {
        int v = (tid >= off) ? s[tid - off] : 0;
        __syncthreads();
        s[tid] += v;
        __syncthreads();
    }
    int e0 = (b > 0) ? s[b - 1] : 0;     // broadcast reads
    int e1 = s[b];
    if (b == 0 && tid == 0) rowptr[N] = E;
    __syncthreads();                      // s[] reused below
    #pragma unroll
    for (int k = 0; k < 16; ++k) cnt[tid + k * 256] = 0;
    __syncthreads();
    for (int e = e0 + tid; e < e1; e += 256) {
        unsigned v = gbin[e];
        atomicAdd(&cnt[((v >> 23) << 3) | ((v >> 14) & 7u)], 1);
    }
    __syncthreads();
    // exclusive scan of 4096: 16 consecutive per thread + 256-scan of partials
    int loc[16];
    int lsum = 0;
    #pragma unroll
    for (int k = 0; k < 16; ++k) { loc[k] = cnt[tid * 16 + k]; lsum += loc[k]; }
    s[tid] = lsum;
    __syncthreads();
    for (int off = 1; off < 256; off <<= 1) {
        int v = (tid >= off) ? s[tid - off] : 0;
        __syncthreads();
        s[tid] += v;
        __syncthreads();
    }
    int run = s[tid] - lsum;
    #pragma unroll
    for (int k = 0; k < 16; ++k) { int t2 = loc[k]; cnt[tid * 16 + k] = run; run += t2; }
    __syncthreads();
    // rowptr/dinv from octant-group boundaries (cnt[i*8] = node i start)
    int n0 = b << BKT_SHIFT;
    #pragma unroll
    for (int i = tid; i < BKT_SIZE; i += 256) {
        int n = n0 + i;
        if (n < N) {
            int st = cnt[i * 8];
            int en = (i == BKT_SIZE - 1) ? (e1 - e0) : cnt[(i + 1) * 8];
            rowptr[n] = e0 + st;
            dinv[n] = rsqrtf((float)(en - st) + 1.0f);   // +1 self-loop
        }
    }
    __syncthreads();    // rowptr reads of cnt complete before cursors mutate
    for (int e = e0 + tid; e < e1; e += 256) {
        unsigned v = gbin[e];
        int p = atomicAdd(&cnt[((v >> 23) << 3) | ((v >> 14) & 7u)], 1);
        col[e0 + p] = (int)(v & 0x7FFFFFu);
    }
}

// ---------------- fused aggregate-1 + gemm2 ----------------
// Phase A (R4-verified gather shape): xw is UNSCALED, so each edge applies
// dinv[src] as an fma scalar (4 B broadcast load from the L2-resident dinv table;
// inner adds become fmas — same VALU throughput). Self term = xw[n]*dinv[n].
// h staged in LDS [32][72]; Phase B unchanged: xws2 = bf16((h @ W2) * dinv).
__global__ __launch_bounds__(256) void k_agg_gemm(const ushort_t* __restrict__ xw,
        const int* __restrict__ rowptr, const int* __restrict__ col,
        const float* __restrict__ dinv, const float* __restrict__ bias,
        const ushort_t* __restrict__ Bp2, ushort_t* __restrict__ out2, int N) {
    __shared__ ushort_t hl[32][72];                 // 4.5 KB, +8 pad breaks 128B stride
    int tid = threadIdx.x;
    int nl = tid >> 3;                              // node-local 0..31
    int i = tid & 7;                                // feature slice 0..7
    int n0 = blockIdx.x * 32;
    int n = n0 + nl;
    u16x8 hz = {};
    if (n < N) {
        int beg = rowptr[n], end = rowptr[n + 1];
        float dn = dinv[n];
        const ushort_t* base = xw + i * 8;
        u16x8 sv = *(const u16x8*)(base + (size_t)n * 64);
        float a[8];
        #pragma unroll
        for (int k = 0; k < 8; ++k) a[k] = bf2f(sv[k]) * dn;   // self: xw[n]*dinv[n]
        int e = beg;
        for (; e + 8 <= end; e += 8) {
            int c[8];
            #pragma unroll
            for (int j = 0; j < 8; ++j) c[j] = col[e + j];
            float dv[8];
            #pragma unroll
            for (int j = 0; j < 8; ++j) dv[j] = dinv[c[j]];
            u16x8 v[8];
            #pragma unroll
            for (int j = 0; j < 8; ++j) v[j] = *(const u16x8*)(base + (size_t)c[j] * 64);
            #pragma unroll
            for (int j = 0; j < 8; ++j)
                #pragma unroll
                for (int k = 0; k < 8; ++k) a[k] += bf2f(v[j][k]) * dv[j];
        }
        if (e + 4 <= end) {
            int c[4];
            #pragma unroll
            for (int j = 0; j < 4; ++j) c[j] = col[e + j];
            float dv[4];
            #pragma unroll
            for (int j = 0; j < 4; ++j) dv[j] = dinv[c[j]];
            u16x8 v[4];
            #pragma unroll
            for (int j = 0; j < 4; ++j) v[j] = *(const u16x8*)(base + (size_t)c[j] * 64);
            #pragma unroll
            for (int j = 0; j < 4; ++j)
                #pragma unroll
                for (int k = 0; k < 8; ++k) a[k] += bf2f(v[j][k]) * dv[j];
            e += 4;
        }
        for (; e < end; ++e) {
            int c = col[e];
            float dv = dinv[c];
            u16x8 v = *(const u16x8*)(base + (size_t)c * 64);
            #pragma unroll
            for (int k = 0; k < 8; ++k) a[k] += bf2f(v[k]) * dv;
        }
        float4 b0 = *(const float4*)(bias + i * 8);
        float4 b1 = *(const float4*)(bias + i * 8 + 4);
        float r[8];
        r[0] = dn * a[0] + b0.x; r[1] = dn * a[1] + b0.y;
        r[2] = dn * a[2] + b0.z; r[3] = dn * a[3] + b0.w;
        r[4] = dn * a[4] + b1.x; r[5] = dn * a[5] + b1.y;
        r[6] = dn * a[6] + b1.z; r[7] = dn * a[7] + b1.w;
        #pragma unroll
        for (int k = 0; k < 8; ++k) hz[k] = f2bf(fmaxf(r[k], 0.f));
    }
    *(u16x8*)&hl[nl][i * 8] = hz;
    __syncthreads();
    // ---- Phase B: xws2[32,64] = bf16((h @ W2) * dinv) via MFMA ----
    int w = tid >> 6, lane = tid & 63;
    int m = lane & 15, q = lane >> 4;
    int mt = w & 1;                  // M-tile (rows mt*16..mt*16+15)
    int nt0 = (w >> 1) << 1;         // this wave's two N-tiles
    f32x4 acc[2] = {};
    #pragma unroll
    for (int s = 0; s < 2; ++s) {
        bf16x8 af = *(const bf16x8*)&hl[mt * 16 + m][s * 32 + q * 8];
        #pragma unroll
        for (int tt = 0; tt < 2; ++tt) {
            bf16x8 bf = *(const bf16x8*)(Bp2 + (size_t)((s * 4 + nt0 + tt) * 64 + lane) * 8);
            acc[tt] = __builtin_amdgcn_mfma_f32_16x16x32_bf16(af, bf, acc[tt], 0, 0, 0);
        }
    }
    // C/D layout: col = lane&15, row = q*4 + r  [m89-verified]
    int orow0 = n0 + mt * 16 + q * 4;
    float4 d4 = *(const float4*)(dinv + orow0);   // ws slack makes OOB read safe
    #pragma unroll
    for (int r = 0; r < 4; ++r) {
        int row = orow0 + r;
        if (row < N) {
            float dn = (r == 0) ? d4.x : (r == 1) ? d4.y : (r == 2) ? d4.z : d4.w;
            #pragma unroll
            for (int tt = 0; tt < 2; ++tt)
                out2[(size_t)row * 64 + (nt0 + tt) * 16 + m] = f2bf(acc[tt][r] * dn);
        }
    }
}

// ---------------- pull aggregation (layer 2 final): R4-verified pattern --------------
// xws2 is pre-scaled by dinv[src] (agg_gemm phase B), so this stays add-only.
__global__ __launch_bounds__(256) void k_aggregate(const ushort_t* __restrict__ xws,
        const int* __restrict__ rowptr, const int* __restrict__ col,
        const float* __restrict__ dinv, const float* __restrict__ bias,
        float* __restrict__ outf, int N) {
    int n = (blockIdx.x * 256 + threadIdx.x) >> 3;
    int i = threadIdx.x & 7;
    if (n >= N) return;
    int beg = rowptr[n], end = rowptr[n + 1];
    float dn = dinv[n];
    const ushort_t* base = xws + i * 8;
    u16x8 sv = *(const u16x8*)(base + (size_t)n * 64);
    float a[8];
    #pragma unroll
    for (int k = 0; k < 8; ++k) a[k] = bf2f(sv[k]);   // self-loop term
    int e = beg;
    for (; e + 8 <= end; e += 8) {
        int c[8];
        #pragma unroll
        for (int j = 0; j < 8; ++j) c[j] = col[e + j];
        u16x8 v[8];
        #pragma unroll
        for (int j = 0; j < 8; ++j) v[j] = *(const u16x8*)(base + (size_t)c[j] * 64);
        #pragma unroll
        for (int j = 0; j < 8; ++j)
            #pragma unroll
            for (int k = 0; k < 8; ++k) a[k] += bf2f(v[j][k]);
    }
    if (e + 4 <= end) {
        int c[4];
        #pragma unroll
        for (int j = 0; j < 4; ++j) c[j] = col[e + j];
        u16x8 v[4];
        #pragma unroll
        for (int j = 0; j < 4; ++j) v[j] = *(const u16x8*)(base + (size_t)c[j] * 64);
        #pragma unroll
        for (int j = 0; j < 4; ++j)
            #pragma unroll
            for (int k = 0; k < 8; ++k) a[k] += bf2f(v[j][k]);
        e += 4;
    }
    for (; e < end; ++e) {
        u16x8 v = *(const u16x8*)(base + (size_t)col[e] * 64);
        #pragma unroll
        for (int k = 0; k < 8; ++k) a[k] += bf2f(v[k]);
    }
    float4 b0 = *(const float4*)(bias + i * 8);
    float4 b1 = *(const float4*)(bias + i * 8 + 4);
    float4 o0 = {dn * a[0] + b0.x, dn * a[1] + b0.y, dn * a[2] + b0.z, dn * a[3] + b0.w};
    float4 o1 = {dn * a[4] + b1.x, dn * a[5] + b1.y, dn * a[6] + b1.z, dn * a[7] + b1.w};
    *(float4*)(outf + (size_t)n * 64 + i * 8) = o0;
    *(float4*)(outf + (size_t)n * 64 + i * 8 + 4) = o1;
}

// ---------------- launch ----------------

extern "C" void kernel_launch(void* const* d_in, const int* in_sizes, int n_in,
                              void* d_out, int out_size, void* d_ws, size_t ws_size,
                              hipStream_t stream) {
    const float* x  = (const float*)d_in[0];
    const int*   ei = (const int*)d_in[1];
    const float* W1 = (const float*)d_in[2];
    const float* b1 = (const float*)d_in[3];
    const float* W2 = (const float*)d_in[4];
    const float* b2 = (const float*)d_in[5];
    float* out = (float*)d_out;

    const int N = in_sizes[0] / IN_F;
    const int E = in_sizes[1] / 2;
    const int* src = ei;        // edge_index[0]
    const int* dst = ei + E;    // edge_index[1]

    char* ws = (char*)d_ws;
    const size_t MB = 1u << 20;
    int*      gcount  = (int*)     (ws + 12288);             // 256 ints
    ushort_t* Bp1     = (ushort_t*)(ws + 16384);             // 8192 bf16 (16 KB)
    ushort_t* Bp2     = (ushort_t*)(ws + 49152);             // 4096 bf16 (8 KB)
    int*      rowptr  = (int*)     (ws + 1 * MB);            // N+1 ints
    float*    dinv    = (float*)   (ws + 2 * MB);            // N floats (+slack)
    unsigned* gbin    = (unsigned*)(ws + 3 * MB);            // E uints (6.4 MB)
    int*      ghist   = (int*)     (ws + 10 * MB);           // nbE*256 ints (~400 KB)
    int*      col     = (int*)     (ws + 11 * MB);           // E ints  (6.4 MB)
    ushort_t* xw      = (ushort_t*)(ws + 20 * MB);           // N*64 bf16 (12.8 MB), unscaled
    ushort_t* xws2    = (ushort_t*)(ws + 36 * MB);           // N*64 bf16 (12.8 MB)

    const int nbE = (E + CHUNK - 1) / CHUNK;                 // 391 (<= 512 for colscan)
    const int nbB = (N + BKT_SIZE - 1) / BKT_SIZE;           // 196 buckets (<= 256)
    const int nbG = (N + 63) / 64;                           // gemm1 blocks total
    const int nbA = (N * 8 + 255) / 256;                     // aggregate blocks

    // split gemm1's blocks across the latency-bound CSR launches
    const int g0 = (nbG < 300) ? nbG : 300;                  // -> colscan
    const int g1 = nbG - g0;                                 // -> scatter

    k_hist_pack<<<nbE + 48, 256, 0, stream>>>(dst, ghist, E, nbE, W1, W2, Bp1, Bp2);
    k_colscan<<<256 + g0, 256, 0, stream>>>(ghist, gcount, nbE, x, Bp1, xw, N, 0);
    k_scatter<<<nbE + g1, 256, 0, stream>>>(src, dst, ghist, gcount, gbin, E, nbE,
                                            x, Bp1, xw, N, g0);
    k_fill2  <<<nbB, 256, 0, stream>>>(gbin, gcount, rowptr, dinv, col, N, E);

    // fused: h = relu(dinv*(sum_e xw[src]*dinv[src] + xw[n]*dinv[n]) + b1) (LDS)
    //        xws2 = bf16((h @ W2) * dinv)
    k_agg_gemm<<<nbA, 256, 0, stream>>>(xw, rowptr, col, dinv, b1, Bp2, xws2, N);
    // layer 2 aggregate: out = dinv*(sum+self) + b2  (fp32)
    k_aggregate<<<nbA, 256, 0, stream>>>(xws2, rowptr, col, dinv, b2, out, N);
}

// Round 16
// 222.909 us; speedup vs baseline: 1.0375x; 1.0375x over previous
//
#include <hip/hip_runtime.h>

#define IN_F 128
#define HID_F 64
#define BKT_SHIFT 9            // 512 nodes per bucket (R4-verified geometry)
#define BKT_SIZE 512
#define CHUNK 4096             // edges per block in binning kernels

typedef unsigned short ushort_t;
typedef __attribute__((ext_vector_type(8))) short bf16x8;
typedef __attribute__((ext_vector_type(8))) unsigned short u16x8;
typedef __attribute__((ext_vector_type(4))) float f32x4;

__device__ inline ushort_t f2bf(float f) {     // RNE fp32 -> bf16 bits
    unsigned u = __float_as_uint(f);
    u += 0x7FFFu + ((u >> 16) & 1u);
    return (ushort_t)(u >> 16);
}
__device__ inline float bf2f(ushort_t u) {
    return __uint_as_float((unsigned)u << 16);
}

// ---------------- CSR build: atomic-free 2-level bucket sort by dst ----------------
// pack: (dst & 511) << 23 | src   (needs src < 2^23, nodes/bucket <= 512)
// R13-verified structure. Ledger of refuted alternatives: nt hints (-21us), 256-bkt
// CSR (-13us), coop grid.sync (-230us), slice-sharding (-65..80us), global deg
// atomics (-47us), NH=2048 sub-buckets (-20us), per-edge dinv + gemm1 appending
// (-8us, R14). Octant sort via fill2 LDS counting = +6us (R13).

__global__ __launch_bounds__(256) void k_hist_pack(const int* __restrict__ dst,
        int* __restrict__ ghist, int E, int nbE,
        const float* __restrict__ W1, const float* __restrict__ W2,
        ushort_t* __restrict__ Bp1, ushort_t* __restrict__ Bp2) {
    int tid = threadIdx.x;
    if ((int)blockIdx.x >= nbE) {
        // W pre-pack into MFMA B-fragment order (bf16).
        // B-frag (16x16x32): lane holds B[k = (lane>>4)*8 + j][n = lane&15], j=0..7.
        int id = ((int)blockIdx.x - nbE) * 256 + tid;
        int iw = (id < 8192) ? id : id - 8192;
        int j = iw & 7, lane = (iw >> 3) & 63, t = (iw >> 9) & 3, s = iw >> 11;
        int k = s * 32 + ((lane >> 4) << 3) + j;
        int n = t * 16 + (lane & 15);
        if (id < 8192)        Bp1[iw] = f2bf(W1[k * 64 + n]);   // K=128: s in 0..3
        else if (id < 12288)  Bp2[iw] = f2bf(W2[k * 64 + n]);   // K=64 : s in 0..1
        return;
    }
    __shared__ int hist[256];
    hist[tid] = 0;
    __syncthreads();
    int e0 = blockIdx.x * CHUNK, e1 = min(e0 + CHUNK, E);
    for (int e = e0 + tid; e < e1; e += 256)
        atomicAdd(&hist[dst[e] >> BKT_SHIFT], 1);
    __syncthreads();
    ghist[blockIdx.x * 256 + tid] = hist[tid];
}

// 256 blocks, one per bucket: parallel exclusive scan over the nb per-block
// counts of this bucket (2 elements/thread, nb <= 512). totals -> gcount.
__global__ __launch_bounds__(256) void k_colscan(int* __restrict__ ghist,
        int* __restrict__ gcount, int nb) {
    __shared__ int s[256];
    int t = threadIdx.x;
    int b = blockIdx.x;
    int j0 = 2 * t, j1 = 2 * t + 1;
    int v0 = (j0 < nb) ? ghist[j0 * 256 + b] : 0;
    int v1 = (j1 < nb) ? ghist[j1 * 256 + b] : 0;
    int p = v0 + v1;
    s[t] = p;
    __syncthreads();
    for (int off = 1; off < 256; off <<= 1) {
        int v = (t >= off) ? s[t - off] : 0;
        __syncthreads();
        s[t] += v;
        __syncthreads();
    }
    int excl = s[t] - p;
    if (j0 < nb) ghist[j0 * 256 + b] = excl;
    if (j1 < nb) ghist[j1 * 256 + b] = excl + v0;
    if (t == 255) gcount[b] = s[255];
}

// scatter into bucket-contiguous gbin; per-block cursors = ghist offset + bucket
// base (local LDS scan of gcount — k_bscan stays eliminated).
__global__ __launch_bounds__(256) void k_scatter(const int* __restrict__ src,
        const int* __restrict__ dst, const int* __restrict__ ghist,
        const int* __restrict__ gcount, unsigned* __restrict__ gbin, int E) {
    __shared__ int cur[256];
    __shared__ int s[256];
    int tid = threadIdx.x;
    int gc = gcount[tid];
    s[tid] = gc;
    __syncthreads();
    for (int off = 1; off < 256; off <<= 1) {
        int v = (tid >= off) ? s[tid - off] : 0;
        __syncthreads();
        s[tid] += v;
        __syncthreads();
    }
    cur[tid] = ghist[blockIdx.x * 256 + tid] + (s[tid] - gc);
    __syncthreads();
    int e0 = blockIdx.x * CHUNK, e1 = min(e0 + CHUNK, E);
    for (int e = e0 + tid; e < e1; e += 256) {
        int d = dst[e];
        int b = d >> BKT_SHIFT;
        int p = atomicAdd(&cur[b], 1);
        gbin[p] = ((unsigned)(d & (BKT_SIZE - 1)) << 23) | (unsigned)src[e];
    }
}

// one block per bucket: per-(node,octant) LDS counting sort.
// key = (node-local)*8 + src-octant (src bits 14..16, already in the gbin word).
// Count pass -> 4096-scan (16/thread + 256-scan) -> rowptr/dinv from group
// boundaries -> single scatter with 4096 cursors. col comes out exactly
// octant-sorted per row (R11/R12/R13 all measured octant-sorted col = faster
// aggregates; this implementation's sort cost is ~free).
__global__ __launch_bounds__(256) void k_fill2(const unsigned* __restrict__ gbin,
        const int* __restrict__ gcount, int* __restrict__ rowptr,
        float* __restrict__ dinv, int* __restrict__ col, int N, int E) {
    __shared__ int cnt[4096];            // 16 KB: 512 nodes x 8 octants
    __shared__ int s[256];
    int tid = threadIdx.x;
    int b = blockIdx.x;
    // bucket window [e0, e1) from local scan of gcount
    int gc = gcount[tid];
    s[tid] = gc;
    __syncthreads();
    for (int off = 1; off < 256; off <<= 1) {
        int v = (tid >= off) ? s[tid - off] : 0;
        __syncthreads();
        s[tid] += v;
        __syncthreads();
    }
    int e0 = (b > 0) ? s[b - 1] : 0;     // broadcast reads
    int e1 = s[b];
    if (b == 0 && tid == 0) rowptr[N] = E;
    __syncthreads();                      // s[] reused below
    #pragma unroll
    for (int k = 0; k < 16; ++k) cnt[tid + k * 256] = 0;
    __syncthreads();
    for (int e = e0 + tid; e < e1; e += 256) {
        unsigned v = gbin[e];
        atomicAdd(&cnt[((v >> 23) << 3) | ((v >> 14) & 7u)], 1);
    }
    __syncthreads();
    // exclusive scan of 4096: 16 consecutive per thread + 256-scan of partials
    int loc[16];
    int lsum = 0;
    #pragma unroll
    for (int k = 0; k < 16; ++k) { loc[k] = cnt[tid * 16 + k]; lsum += loc[k]; }
    s[tid] = lsum;
    __syncthreads();
    for (int off = 1; off < 256; off <<= 1) {
        int v = (tid >= off) ? s[tid - off] : 0;
        __syncthreads();
        s[tid] += v;
        __syncthreads();
    }
    int run = s[tid] - lsum;
    #pragma unroll
    for (int k = 0; k < 16; ++k) { int t2 = loc[k]; cnt[tid * 16 + k] = run; run += t2; }
    __syncthreads();
    // rowptr/dinv from octant-group boundaries (cnt[i*8] = node i start)
    int n0 = b << BKT_SHIFT;
    #pragma unroll
    for (int i = tid; i < BKT_SIZE; i += 256) {
        int n = n0 + i;
        if (n < N) {
            int st = cnt[i * 8];
            int en = (i == BKT_SIZE - 1) ? (e1 - e0) : cnt[(i + 1) * 8];
            rowptr[n] = e0 + st;
            dinv[n] = rsqrtf((float)(en - st) + 1.0f);   // +1 self-loop
        }
    }
    __syncthreads();    // rowptr reads of cnt complete before cursors mutate
    for (int e = e0 + tid; e < e1; e += 256) {
        unsigned v = gbin[e];
        int p = atomicAdd(&cnt[((v >> 23) << 3) | ((v >> 14) & 7u)], 1);
        col[e0 + p] = (int)(v & 0x7FFFFFu);
    }
}

// ---------------- MFMA GEMM: out[N,64] = bf16((A[N,K] @ W) * dinv[row]) ----------------
template<int K, typename AT>
__global__ __launch_bounds__(256) void k_gemm_mfma(const AT* __restrict__ A,
        const ushort_t* __restrict__ Bp, const float* __restrict__ dinv,
        ushort_t* __restrict__ out, int N) {
    int wave = threadIdx.x >> 6, lane = threadIdx.x & 63;
    int m = lane & 15, q = lane >> 4;
    int row0 = blockIdx.x * 64 + wave * 16;
    int arow = row0 + m;
    int arowc = (arow < N) ? arow : (N - 1);
    f32x4 acc[4] = {};
    #pragma unroll
    for (int s = 0; s < K / 32; ++s) {
        bf16x8 af;
        if constexpr (sizeof(AT) == 4) {
            const float* ap = (const float*)A + (size_t)arowc * K + s * 32 + q * 8;
            float4 x0 = *(const float4*)ap;
            float4 x1 = *(const float4*)(ap + 4);
            af[0] = (short)f2bf(x0.x); af[1] = (short)f2bf(x0.y);
            af[2] = (short)f2bf(x0.z); af[3] = (short)f2bf(x0.w);
            af[4] = (short)f2bf(x1.x); af[5] = (short)f2bf(x1.y);
            af[6] = (short)f2bf(x1.z); af[7] = (short)f2bf(x1.w);
        } else {
            af = *(const bf16x8*)((const ushort_t*)A + (size_t)arowc * K + s * 32 + q * 8);
        }
        #pragma unroll
        for (int t = 0; t < 4; ++t) {
            bf16x8 bf = *(const bf16x8*)(Bp + (size_t)((s * 4 + t) * 64 + lane) * 8);
            acc[t] = __builtin_amdgcn_mfma_f32_16x16x32_bf16(af, bf, acc[t], 0, 0, 0);
        }
    }
    // C/D layout: col = lane&15, row = q*4 + r  [m89-verified]
    int orow0 = row0 + q * 4;
    float4 d4 = *(const float4*)(dinv + orow0);   // ws slack makes OOB read safe
    #pragma unroll
    for (int r = 0; r < 4; ++r) {
        int row = orow0 + r;
        if (row < N) {
            float dn = (r == 0) ? d4.x : (r == 1) ? d4.y : (r == 2) ? d4.z : d4.w;
            #pragma unroll
            for (int t = 0; t < 4; ++t)
                out[(size_t)row * 64 + t * 16 + m] = f2bf(acc[t][r] * dn);
        }
    }
}

// ---------------- fused aggregate-1 + gemm2 (R9-verified) ----------------
// Phase A: R4-verified gather (8 lanes/node, 8-edge unroll, full-line 128 B reads);
// h staged in LDS [32][72]. Phase B: 4 MFMA/wave against Bp2 -> xws2.
__global__ __launch_bounds__(256) void k_agg_gemm(const ushort_t* __restrict__ xws,
        const int* __restrict__ rowptr, const int* __restrict__ col,
        const float* __restrict__ dinv, const float* __restrict__ bias,
        const ushort_t* __restrict__ Bp2, ushort_t* __restrict__ out2, int N) {
    __shared__ ushort_t hl[32][72];                 // 4.5 KB, +8 pad breaks 128B stride
    int tid = threadIdx.x;
    int nl = tid >> 3;                              // node-local 0..31
    int i = tid & 7;                                // feature slice 0..7
    int n0 = blockIdx.x * 32;
    int n = n0 + nl;
    u16x8 hz = {};
    if (n < N) {
        int beg = rowptr[n], end = rowptr[n + 1];
        float dn = dinv[n];
        const ushort_t* base = xws + i * 8;
        u16x8 sv = *(const u16x8*)(base + (size_t)n * 64);
        float a[8];
        #pragma unroll
        for (int k = 0; k < 8; ++k) a[k] = bf2f(sv[k]);   // self-loop term
        int e = beg;
        for (; e + 8 <= end; e += 8) {
            int c[8];
            #pragma unroll
            for (int j = 0; j < 8; ++j) c[j] = col[e + j];
            u16x8 v[8];
            #pragma unroll
            for (int j = 0; j < 8; ++j) v[j] = *(const u16x8*)(base + (size_t)c[j] * 64);
            #pragma unroll
            for (int j = 0; j < 8; ++j)
                #pragma unroll
                for (int k = 0; k < 8; ++k) a[k] += bf2f(v[j][k]);
        }
        if (e + 4 <= end) {
            int c[4];
            #pragma unroll
            for (int j = 0; j < 4; ++j) c[j] = col[e + j];
            u16x8 v[4];
            #pragma unroll
            for (int j = 0; j < 4; ++j) v[j] = *(const u16x8*)(base + (size_t)c[j] * 64);
            #pragma unroll
            for (int j = 0; j < 4; ++j)
                #pragma unroll
                for (int k = 0; k < 8; ++k) a[k] += bf2f(v[j][k]);
            e += 4;
        }
        for (; e < end; ++e) {
            u16x8 v = *(const u16x8*)(base + (size_t)col[e] * 64);
            #pragma unroll
            for (int k = 0; k < 8; ++k) a[k] += bf2f(v[k]);
        }
        float4 b0 = *(const float4*)(bias + i * 8);
        float4 b1 = *(const float4*)(bias + i * 8 + 4);
        float r[8];
        r[0] = dn * a[0] + b0.x; r[1] = dn * a[1] + b0.y;
        r[2] = dn * a[2] + b0.z; r[3] = dn * a[3] + b0.w;
        r[4] = dn * a[4] + b1.x; r[5] = dn * a[5] + b1.y;
        r[6] = dn * a[6] + b1.z; r[7] = dn * a[7] + b1.w;
        #pragma unroll
        for (int k = 0; k < 8; ++k) hz[k] = f2bf(fmaxf(r[k], 0.f));
    }
    *(u16x8*)&hl[nl][i * 8] = hz;
    __syncthreads();
    // ---- Phase B: xws2[32,64] = bf16((h @ W2) * dinv) via MFMA ----
    int w = tid >> 6, lane = tid & 63;
    int m = lane & 15, q = lane >> 4;
    int mt = w & 1;                  // M-tile (rows mt*16..mt*16+15)
    int nt0 = (w >> 1) << 1;         // this wave's two N-tiles
    f32x4 acc[2] = {};
    #pragma unroll
    for (int s = 0; s < 2; ++s) {
        bf16x8 af = *(const bf16x8*)&hl[mt * 16 + m][s * 32 + q * 8];
        #pragma unroll
        for (int tt = 0; tt < 2; ++tt) {
            bf16x8 bf = *(const bf16x8*)(Bp2 + (size_t)((s * 4 + nt0 + tt) * 64 + lane) * 8);
            acc[tt] = __builtin_amdgcn_mfma_f32_16x16x32_bf16(af, bf, acc[tt], 0, 0, 0);
        }
    }
    // C/D layout: col = lane&15, row = q*4 + r  [m89-verified]
    int orow0 = n0 + mt * 16 + q * 4;
    float4 d4 = *(const float4*)(dinv + orow0);
    #pragma unroll
    for (int r = 0; r < 4; ++r) {
        int row = orow0 + r;
        if (row < N) {
            float dn = (r == 0) ? d4.x : (r == 1) ? d4.y : (r == 2) ? d4.z : d4.w;
            #pragma unroll
            for (int tt = 0; tt < 2; ++tt)
                out2[(size_t)row * 64 + (nt0 + tt) * 16 + m] = f2bf(acc[tt][r] * dn);
        }
    }
}

// ---------------- pull aggregation (layer 2 final): R4-verified pattern --------------
__global__ __launch_bounds__(256) void k_aggregate(const ushort_t* __restrict__ xws,
        const int* __restrict__ rowptr, const int* __restrict__ col,
        const float* __restrict__ dinv, const float* __restrict__ bias,
        float* __restrict__ outf, int N) {
    int n = (blockIdx.x * 256 + threadIdx.x) >> 3;
    int i = threadIdx.x & 7;
    if (n >= N) return;
    int beg = rowptr[n], end = rowptr[n + 1];
    float dn = dinv[n];
    const ushort_t* base = xws + i * 8;
    u16x8 sv = *(const u16x8*)(base + (size_t)n * 64);
    float a[8];
    #pragma unroll
    for (int k = 0; k < 8; ++k) a[k] = bf2f(sv[k]);   // self-loop term
    int e = beg;
    for (; e + 8 <= end; e += 8) {
        int c[8];
        #pragma unroll
        for (int j = 0; j < 8; ++j) c[j] = col[e + j];
        u16x8 v[8];
        #pragma unroll
        for (int j = 0; j < 8; ++j) v[j] = *(const u16x8*)(base + (size_t)c[j] * 64);
        #pragma unroll
        for (int j = 0; j < 8; ++j)
            #pragma unroll
            for (int k = 0; k < 8; ++k) a[k] += bf2f(v[j][k]);
    }
    if (e + 4 <= end) {
        int c[4];
        #pragma unroll
        for (int j = 0; j < 4; ++j) c[j] = col[e + j];
        u16x8 v[4];
        #pragma unroll
        for (int j = 0; j < 4; ++j) v[j] = *(const u16x8*)(base + (size_t)c[j] * 64);
        #pragma unroll
        for (int j = 0; j < 4; ++j)
            #pragma unroll
            for (int k = 0; k < 8; ++k) a[k] += bf2f(v[j][k]);
        e += 4;
    }
    for (; e < end; ++e) {
        u16x8 v = *(const u16x8*)(base + (size_t)col[e] * 64);
        #pragma unroll
        for (int k = 0; k < 8; ++k) a[k] += bf2f(v[k]);
    }
    float4 b0 = *(const float4*)(bias + i * 8);
    float4 b1 = *(const float4*)(bias + i * 8 + 4);
    float4 o0 = {dn * a[0] + b0.x, dn * a[1] + b0.y, dn * a[2] + b0.z, dn * a[3] + b0.w};
    float4 o1 = {dn * a[4] + b1.x, dn * a[5] + b1.y, dn * a[6] + b1.z, dn * a[7] + b1.w};
    *(float4*)(outf + (size_t)n * 64 + i * 8) = o0;
    *(float4*)(outf + (size_t)n * 64 + i * 8 + 4) = o1;
}

// ---------------- launch ----------------

extern "C" void kernel_launch(void* const* d_in, const int* in_sizes, int n_in,
                              void* d_out, int out_size, void* d_ws, size_t ws_size,
                              hipStream_t stream) {
    const float* x  = (const float*)d_in[0];
    const int*   ei = (const int*)d_in[1];
    const float* W1 = (const float*)d_in[2];
    const float* b1 = (const float*)d_in[3];
    const float* W2 = (const float*)d_in[4];
    const float* b2 = (const float*)d_in[5];
    float* out = (float*)d_out;

    const int N = in_sizes[0] / IN_F;
    const int E = in_sizes[1] / 2;
    const int* src = ei;        // edge_index[0]
    const int* dst = ei + E;    // edge_index[1]

    char* ws = (char*)d_ws;
    const size_t MB = 1u << 20;
    int*      gcount  = (int*)     (ws + 12288);             // 256 ints
    ushort_t* Bp1     = (ushort_t*)(ws + 16384);             // 8192 bf16 (16 KB)
    ushort_t* Bp2     = (ushort_t*)(ws + 49152);             // 4096 bf16 (8 KB)
    int*      rowptr  = (int*)     (ws + 1 * MB);            // N+1 ints
    float*    dinv    = (float*)   (ws + 2 * MB);            // N floats (+slack)
    unsigned* gbin    = (unsigned*)(ws + 3 * MB);            // E uints (6.4 MB)
    int*      ghist   = (int*)     (ws + 10 * MB);           // nbE*256 ints (~400 KB)
    int*      col     = (int*)     (ws + 11 * MB);           // E ints  (6.4 MB)
    ushort_t* xws     = (ushort_t*)(ws + 20 * MB);           // N*64 bf16 (12.8 MB)
    ushort_t* xws2    = (ushort_t*)(ws + 36 * MB);           // N*64 bf16 (12.8 MB)

    const int nbE = (E + CHUNK - 1) / CHUNK;                 // 391 (<= 512 for colscan)
    const int nbB = (N + BKT_SIZE - 1) / BKT_SIZE;           // 196 buckets (<= 256)
    const int nbG = (N + 63) / 64;                           // GEMM blocks
    const int nbA = (N * 8 + 255) / 256;                     // aggregate blocks

    k_hist_pack<<<nbE + 48, 256, 0, stream>>>(dst, ghist, E, nbE, W1, W2, Bp1, Bp2);
    k_colscan<<<256, 256, 0, stream>>>(ghist, gcount, nbE);
    k_scatter<<<nbE, 256, 0, stream>>>(src, dst, ghist, gcount, gbin, E);
    k_fill2  <<<nbB, 256, 0, stream>>>(gbin, gcount, rowptr, dinv, col, N, E);

    // layer 1 GEMM: xws = bf16((x @ W1) * dinv)
    k_gemm_mfma<IN_F, float><<<nbG, 256, 0, stream>>>(x, Bp1, dinv, xws, N);
    // fused: h = relu(dinv*(sum+self)+b1) (LDS only) ; xws2 = bf16((h @ W2) * dinv)
    k_agg_gemm<<<nbA, 256, 0, stream>>>(xws, rowptr, col, dinv, b1, Bp2, xws2, N);
    // layer 2 aggregate: out = dinv*(sum+self) + b2  (fp32)
    k_aggregate<<<nbA, 256, 0, stream>>>(xws2, rowptr, col, dinv, b2, out, N);
}